// Round 3
// baseline (4588.403 us; speedup 1.0000x reference)
//
#include <hip/hip_runtime.h>
#include <cstddef>

#define DD 128
#define EPS 1e-5f
#define BROWS 128          // rows per bucket (must be 128: row_local packed in 7 bits)
#define MAXB 1024          // max buckets supported by hist/scan LDS

typedef short short8 __attribute__((ext_vector_type(8)));
typedef float float4v __attribute__((ext_vector_type(4)));

__device__ __forceinline__ unsigned short f2bf(float f) {
    union { float f; unsigned int u; } x; x.f = f;
    unsigned int r = x.u + 0x7fffu + ((x.u >> 16) & 1u);   // RNE
    return (unsigned short)(r >> 16);
}
__device__ __forceinline__ float bfhi2f(unsigned int hi_bits) {
    union { unsigned int u; float f; } x; x.u = hi_bits;
    return x.f;
}

// ---------------- bucket histogram (LDS-staged) ----------------

__global__ __launch_bounds__(256) void bhist_kernel(const int* __restrict__ row,
                                                    int* __restrict__ bcnt, int E) {
    __shared__ int bins[MAXB];
    for (int i = threadIdx.x; i < MAXB; i += 256) bins[i] = 0;
    __syncthreads();
    for (int e = blockIdx.x * 256 + threadIdx.x; e < E; e += gridDim.x * 256)
        atomicAdd(&bins[row[e] >> 7], 1);
    __syncthreads();
    for (int i = threadIdx.x; i < MAXB; i += 256) {
        int v = bins[i];
        if (v) atomicAdd(&bcnt[i], v);
    }
}

// ---------------- scan over buckets (single block) ----------------

__global__ __launch_bounds__(1024) void bscan_kernel(const int* __restrict__ bcnt,
                                                     int* __restrict__ bstart,
                                                     int* __restrict__ cursor, int B) {
    __shared__ int s[1024];
    int tid = threadIdx.x;
    int v = (tid < B) ? bcnt[tid] : 0;
    s[tid] = v;
    __syncthreads();
    for (int off = 1; off < 1024; off <<= 1) {
        int t = s[tid];
        int u = (tid >= off) ? s[tid - off] : 0;
        __syncthreads();
        s[tid] = t + u;
        __syncthreads();
    }
    if (tid < B) {
        int st = s[tid] - v;
        bstart[tid] = st;
        cursor[tid] = st;
    }
    if (tid == B - 1) bstart[B] = s[tid];
}

// ---------------- binning scatter: packed 8B records ----------------
// pk.x = (row&127)<<17 | col  (col < 2^17), pk.y = bits(w)

__global__ __launch_bounds__(256) void bin_kernel(const int* __restrict__ row,
                                                  const int* __restrict__ col,
                                                  const float* __restrict__ ew,
                                                  int* __restrict__ cursor,
                                                  uint2* __restrict__ ebuf, int E) {
    int e = blockIdx.x * 256 + threadIdx.x;
    if (e < E) {
        int r = row[e];
        int p = atomicAdd(&cursor[r >> 7], 1);
        uint2 pk;
        pk.x = ((unsigned int)(r & 127) << 17) | (unsigned int)col[e];
        pk.y = __float_as_uint(ew[e]);
        ebuf[p] = pk;
    }
}

// ---------------- W -> W^T bf16 ----------------

__global__ void convw_kernel(const float* __restrict__ W0, const float* __restrict__ W1,
                             const float* __restrict__ W2, unsigned short* __restrict__ T0,
                             unsigned short* __restrict__ T1, unsigned short* __restrict__ T2) {
    const float* W = (blockIdx.y == 0) ? W0 : (blockIdx.y == 1) ? W1 : W2;
    unsigned short* T = (blockIdx.y == 0) ? T0 : (blockIdx.y == 1) ? T1 : T2;
    int gid = blockIdx.x * 256 + threadIdx.x;
    int k = gid >> 7, n = gid & 127;
    T[n * DD + k] = f2bf(W[k * DD + n]);
}

// ---------------- MFMA GEMM: H_bf16 = f(A_fp32) @ W + b ----------------

__global__ __launch_bounds__(256) void gemm_mfma_kernel(
    const float* __restrict__ A, const unsigned short* __restrict__ Wt,
    const float* __restrict__ bias,
    const float* __restrict__ scale, const float* __restrict__ shift,
    int doBN, unsigned short* __restrict__ H, int nrows)
{
    __shared__ unsigned short Asl[64][136];
    __shared__ unsigned short Wsl[128][136];

    const int tid  = threadIdx.x;
    const int row0 = blockIdx.x * 64;

    for (int i = tid; i < 2048; i += 256) {
        int r = i >> 4, off = (i & 15) * 8;
        *(uint4*)&Wsl[r][off] = *(const uint4*)(Wt + (size_t)r * DD + off);
    }
    for (int i = tid; i < 2048; i += 256) {
        int r = i >> 5, off4 = i & 31;
        int grow = row0 + r;
        float4 v = make_float4(0.f, 0.f, 0.f, 0.f);
        if (grow < nrows)
            v = *(const float4*)(A + (size_t)grow * DD + off4 * 4);
        if (doBN) {
            float4 sc = *(const float4*)(scale + off4 * 4);
            float4 sh = *(const float4*)(shift + off4 * 4);
            v.x = fmaxf(0.f, v.x * sc.x + sh.x);
            v.y = fmaxf(0.f, v.y * sc.y + sh.y);
            v.z = fmaxf(0.f, v.z * sc.z + sh.z);
            v.w = fmaxf(0.f, v.w * sc.w + sh.w);
        }
        ushort4 p;
        p.x = f2bf(v.x); p.y = f2bf(v.y); p.z = f2bf(v.z); p.w = f2bf(v.w);
        *(ushort4*)&Asl[r][off4 * 4] = p;
    }
    __syncthreads();

    const int w = tid >> 6, lane = tid & 63;
    const int m = lane & 15, q = lane >> 4;

    short8 afr[4];
    #pragma unroll
    for (int c = 0; c < 4; ++c)
        afr[c] = *(const short8*)&Asl[w * 16 + m][c * 32 + q * 8];

    float4v acc[8];
    #pragma unroll
    for (int t = 0; t < 8; ++t) acc[t] = (float4v){0.f, 0.f, 0.f, 0.f};

    #pragma unroll
    for (int t = 0; t < 8; ++t) {
        #pragma unroll
        for (int c = 0; c < 4; ++c) {
            short8 bfr = *(const short8*)&Wsl[t * 16 + m][c * 32 + q * 8];
            acc[t] = __builtin_amdgcn_mfma_f32_16x16x32_bf16(afr[c], bfr, acc[t], 0, 0, 0);
        }
    }

    #pragma unroll
    for (int t = 0; t < 8; ++t) {
        float bv = bias[t * 16 + m];
        #pragma unroll
        for (int i = 0; i < 4; ++i)
            Asl[w * 16 + q * 4 + i][t * 16 + m] = f2bf(acc[t][i] + bv);
    }
    __syncthreads();

    for (int i = tid; i < 1024; i += 256) {
        int r = i >> 4, off = (i & 15) * 8;
        if (row0 + r < nrows)
            *(uint4*)(H + (size_t)(row0 + r) * DD + off) = *(const uint4*)&Asl[r][off];
    }
}

// ---------------- fused binned SpMM (+optional BN stats) ----------------
// One block per 128-row bucket. 512 threads = 8 waves; wave handles edges e0+wv step 8.
// Accumulate w*H[col] into 64KB LDS tile via ds_add_f32, then coalesced writeout.

__global__ __launch_bounds__(512) void spmm_binned_kernel(
    const unsigned short* __restrict__ H, const uint2* __restrict__ ebuf,
    const int* __restrict__ bstart, float* __restrict__ S,
    float* __restrict__ sums, int doStats, int N)
{
    __shared__ float Sl[BROWS * DD];   // 64 KB

    const int tid = threadIdx.x;
    const int b = blockIdx.x;
    const int rbase = b * BROWS;

    #pragma unroll
    for (int i = tid; i < BROWS * DD / 4; i += 512)
        *(float4*)&Sl[i * 4] = make_float4(0.f, 0.f, 0.f, 0.f);
    __syncthreads();

    const int wv = tid >> 6, lane = tid & 63;
    const int ch = lane * 2;
    const int e0 = bstart[b], e1 = bstart[b + 1];

    int e = e0 + wv;
    for (; e + 24 < e1; e += 32) {
        uint2 d0 = ebuf[e];
        uint2 d1 = ebuf[e + 8];
        uint2 d2 = ebuf[e + 16];
        uint2 d3 = ebuf[e + 24];
        unsigned int u0 = *(const unsigned int*)(H + (size_t)(d0.x & 0x1FFFFu) * DD + ch);
        unsigned int u1 = *(const unsigned int*)(H + (size_t)(d1.x & 0x1FFFFu) * DD + ch);
        unsigned int u2 = *(const unsigned int*)(H + (size_t)(d2.x & 0x1FFFFu) * DD + ch);
        unsigned int u3 = *(const unsigned int*)(H + (size_t)(d3.x & 0x1FFFFu) * DD + ch);
        float w0 = __uint_as_float(d0.y), w1 = __uint_as_float(d1.y);
        float w2 = __uint_as_float(d2.y), w3 = __uint_as_float(d3.y);
        int r0 = (d0.x >> 17) * DD + ch, r1 = (d1.x >> 17) * DD + ch;
        int r2 = (d2.x >> 17) * DD + ch, r3 = (d3.x >> 17) * DD + ch;
        atomicAdd(&Sl[r0],     w0 * bfhi2f(u0 << 16));
        atomicAdd(&Sl[r0 + 1], w0 * bfhi2f(u0 & 0xffff0000u));
        atomicAdd(&Sl[r1],     w1 * bfhi2f(u1 << 16));
        atomicAdd(&Sl[r1 + 1], w1 * bfhi2f(u1 & 0xffff0000u));
        atomicAdd(&Sl[r2],     w2 * bfhi2f(u2 << 16));
        atomicAdd(&Sl[r2 + 1], w2 * bfhi2f(u2 & 0xffff0000u));
        atomicAdd(&Sl[r3],     w3 * bfhi2f(u3 << 16));
        atomicAdd(&Sl[r3 + 1], w3 * bfhi2f(u3 & 0xffff0000u));
    }
    for (; e < e1; e += 8) {
        uint2 d0 = ebuf[e];
        unsigned int u0 = *(const unsigned int*)(H + (size_t)(d0.x & 0x1FFFFu) * DD + ch);
        float w0 = __uint_as_float(d0.y);
        int r0 = (d0.x >> 17) * DD + ch;
        atomicAdd(&Sl[r0],     w0 * bfhi2f(u0 << 16));
        atomicAdd(&Sl[r0 + 1], w0 * bfhi2f(u0 & 0xffff0000u));
    }
    __syncthreads();

    const int nrows = min(BROWS, N - rbase);
    for (int i = tid; i < nrows * (DD / 4); i += 512) {
        int r = i >> 5, c4 = (i & 31) * 4;
        *(float4*)(S + (size_t)(rbase + r) * DD + c4) = *(const float4*)&Sl[r * DD + c4];
    }

    if (doStats) {
        // per-channel partial sums over this bucket's rows (zero rows contribute 0)
        const int c = tid & 127, quarter = tid >> 7;
        float s = 0.f, s2 = 0.f;
        #pragma unroll 4
        for (int r = quarter * 32; r < quarter * 32 + 32; ++r) {
            float v = Sl[r * DD + c];
            s += v; s2 += v * v;
        }
        __syncthreads();                 // all reads of Sl done before reuse
        Sl[tid] = s;
        Sl[512 + tid] = s2;
        __syncthreads();
        if (tid < 128) {
            float ts = Sl[c] + Sl[128 + c] + Sl[256 + c] + Sl[384 + c];
            float t2 = Sl[512 + c] + Sl[640 + c] + Sl[768 + c] + Sl[896 + c];
            atomicAdd(&sums[c], ts);
            atomicAdd(&sums[128 + c], t2);
        }
    }
}

// ---------------- BN finalize ----------------

__global__ void bn_final_kernel(const float* __restrict__ sums, const float* __restrict__ g,
                                const float* __restrict__ be, float* __restrict__ scl,
                                float* __restrict__ sft, int n) {
    int c = threadIdx.x;
    float mean = sums[c] / (float)n;
    float var = sums[128 + c] / (float)n - mean * mean;
    float rstd = rsqrtf(var + EPS);
    float sc = g[c] * rstd;
    scl[c] = sc;
    sft[c] = be[c] - mean * sc;
}

// ---------------- launch ----------------

extern "C" void kernel_launch(void* const* d_in, const int* in_sizes, int n_in,
                              void* d_out, int out_size, void* d_ws, size_t ws_size,
                              hipStream_t stream) {
    const float* x   = (const float*)d_in[0];
    const float* ew  = (const float*)d_in[1];
    const float* W0  = (const float*)d_in[2];
    const float* b0  = (const float*)d_in[3];
    const float* g0  = (const float*)d_in[4];
    const float* be0 = (const float*)d_in[5];
    const float* W1  = (const float*)d_in[6];
    const float* b1  = (const float*)d_in[7];
    const float* g1  = (const float*)d_in[8];
    const float* be1 = (const float*)d_in[9];
    const float* W2  = (const float*)d_in[10];
    const float* b2  = (const float*)d_in[11];
    const int* row   = (const int*)d_in[12];
    const int* col   = (const int*)d_in[13];

    const int N = in_sizes[0] / DD;
    const int E = in_sizes[1];
    const int B = (N + BROWS - 1) / BROWS;   // buckets (782 for N=100000, <= MAXB)
    float* out = (float*)d_out;

    char* w = (char*)d_ws;
    unsigned short* H   = (unsigned short*)w; w += (size_t)N * DD * 2;
    uint2* ebuf         = (uint2*)w;          w += (size_t)E * 8;
    unsigned short* Wt0 = (unsigned short*)w; w += DD * DD * 2;
    unsigned short* Wt1 = (unsigned short*)w; w += DD * DD * 2;
    unsigned short* Wt2 = (unsigned short*)w; w += DD * DD * 2;
    float* sums         = (float*)w;          w += 256 * 4;
    float* scl          = (float*)w;          w += 128 * 4;
    float* sft          = (float*)w;          w += 128 * 4;
    int*   bcnt         = (int*)w;            w += (MAXB + 1) * 4;
    int*   bstart       = (int*)w;            w += (MAXB + 1) * 4;
    int*   cursor       = (int*)w;            w += (MAXB + 1) * 4;

    // ---- bucketed edge binning (reused by all 3 SpMMs) ----
    hipMemsetAsync(bcnt, 0, (size_t)B * 4, stream);
    bhist_kernel<<<128, 256, 0, stream>>>(row, bcnt, E);
    bscan_kernel<<<1, 1024, 0, stream>>>(bcnt, bstart, cursor, B);
    bin_kernel<<<(E + 255) / 256, 256, 0, stream>>>(row, col, ew, cursor, ebuf, E);

    // ---- weights -> bf16 transposed ----
    convw_kernel<<<dim3(64, 3), 256, 0, stream>>>(W0, W1, W2, Wt0, Wt1, Wt2);

    int gblocks = (N + 63) / 64;

    // ---- layer 0 ----
    gemm_mfma_kernel<<<gblocks, 256, 0, stream>>>(x, Wt0, b0, nullptr, nullptr, 0, H, N);
    hipMemsetAsync(sums, 0, 256 * 4, stream);
    spmm_binned_kernel<<<B, 512, 0, stream>>>(H, ebuf, bstart, out, sums, 1, N);
    bn_final_kernel<<<1, 128, 0, stream>>>(sums, g0, be0, scl, sft, N);

    // ---- layer 1 ----
    gemm_mfma_kernel<<<gblocks, 256, 0, stream>>>(out, Wt1, b1, scl, sft, 1, H, N);
    hipMemsetAsync(sums, 0, 256 * 4, stream);
    spmm_binned_kernel<<<B, 512, 0, stream>>>(H, ebuf, bstart, out, sums, 1, N);
    bn_final_kernel<<<1, 128, 0, stream>>>(sums, g1, be1, scl, sft, N);

    // ---- layer 2 (no BN/ReLU) ----
    gemm_mfma_kernel<<<gblocks, 256, 0, stream>>>(out, Wt2, b2, scl, sft, 1, H, N);
    spmm_binned_kernel<<<B, 512, 0, stream>>>(H, ebuf, bstart, out, nullptr, 0, N);
}

// Round 4
// 734.538 us; speedup vs baseline: 6.2467x; 6.2467x over previous
//
#include <hip/hip_runtime.h>
#include <cstddef>

#define DD 128
#define EPS 1e-5f

typedef short short8 __attribute__((ext_vector_type(8)));
typedef float float4v __attribute__((ext_vector_type(4)));

__device__ __forceinline__ unsigned short f2bf(float f) {
    union { float f; unsigned int u; } x; x.f = f;
    unsigned int r = x.u + 0x7fffu + ((x.u >> 16) & 1u);   // RNE
    return (unsigned short)(r >> 16);
}
__device__ __forceinline__ float bfhi2f(unsigned int hi_bits) {
    union { unsigned int u; float f; } x; x.u = hi_bits;
    return x.f;
}

// ---------------- CSR build ----------------

__global__ void hist_kernel(const int* __restrict__ row, int* __restrict__ deg, int E) {
    int e = blockIdx.x * blockDim.x + threadIdx.x;
    if (e < E) atomicAdd(&deg[row[e]], 1);
}

__global__ void scanA_kernel(const int* __restrict__ deg, int* __restrict__ tmp,
                             int* __restrict__ bsum, int n) {
    __shared__ int s[1024];
    int tid = threadIdx.x;
    int gid = blockIdx.x * 1024 + tid;
    int v = (gid < n) ? deg[gid] : 0;
    s[tid] = v;
    __syncthreads();
    for (int off = 1; off < 1024; off <<= 1) {
        int t = s[tid];
        int u = (tid >= off) ? s[tid - off] : 0;
        __syncthreads();
        s[tid] = t + u;
        __syncthreads();
    }
    if (gid < n) tmp[gid] = s[tid];
    if (tid == 1023) bsum[blockIdx.x] = s[1023];
}

__global__ void scanB_kernel(const int* __restrict__ bsum, int* __restrict__ boff,
                             int* __restrict__ row_start, int nb, int n) {
    __shared__ int s[128];
    int tid = threadIdx.x;
    int v = (tid < nb) ? bsum[tid] : 0;
    s[tid] = v;
    __syncthreads();
    for (int off = 1; off < 128; off <<= 1) {
        int t = s[tid];
        int u = (tid >= off) ? s[tid - off] : 0;
        __syncthreads();
        s[tid] = t + u;
        __syncthreads();
    }
    if (tid < nb) boff[tid] = s[tid] - v;
    if (tid == nb - 1) row_start[n] = s[tid];
}

__global__ void scanC_kernel(const int* __restrict__ deg, const int* __restrict__ tmp,
                             const int* __restrict__ boff, int* __restrict__ row_start,
                             int* __restrict__ cursor, int n) {
    int gid = blockIdx.x * 1024 + threadIdx.x;
    if (gid < n) {
        int rs = tmp[gid] - deg[gid] + boff[blockIdx.x];
        row_start[gid] = rs;
        cursor[gid] = rs;
    }
}

// packed 8B record per edge: lo32 = col, hi32 = bits(w). Non-temporal store
// (random 8B scatter: bypass L2, avoid thrash; HBM writes are 32B sectors anyway).
__global__ void scatter_kernel(const int* __restrict__ row, const int* __restrict__ col,
                               const float* __restrict__ ew, int* __restrict__ cursor,
                               unsigned long long* __restrict__ ebuf, int E) {
    int e = blockIdx.x * blockDim.x + threadIdx.x;
    if (e < E) {
        int r = row[e];
        int p = atomicAdd(&cursor[r], 1);
        unsigned long long pk = (unsigned long long)(unsigned int)col[e]
                              | ((unsigned long long)__float_as_uint(ew[e]) << 32);
        __builtin_nontemporal_store(pk, &ebuf[p]);
    }
}

// ---------------- W -> W^T bf16 ----------------

__global__ void convw_kernel(const float* __restrict__ W0, const float* __restrict__ W1,
                             const float* __restrict__ W2, unsigned short* __restrict__ T0,
                             unsigned short* __restrict__ T1, unsigned short* __restrict__ T2) {
    const float* W = (blockIdx.y == 0) ? W0 : (blockIdx.y == 1) ? W1 : W2;
    unsigned short* T = (blockIdx.y == 0) ? T0 : (blockIdx.y == 1) ? T1 : T2;
    int gid = blockIdx.x * 256 + threadIdx.x;
    int k = gid >> 7, n = gid & 127;
    T[n * DD + k] = f2bf(W[k * DD + n]);
}

// ---------------- MFMA GEMM: H_bf16 = f(A_fp32) @ W + b ----------------

__global__ __launch_bounds__(256) void gemm_mfma_kernel(
    const float* __restrict__ A, const unsigned short* __restrict__ Wt,
    const float* __restrict__ bias,
    const float* __restrict__ scale, const float* __restrict__ shift,
    int doBN, unsigned short* __restrict__ H, int nrows)
{
    __shared__ unsigned short Asl[64][136];
    __shared__ unsigned short Wsl[128][136];

    const int tid  = threadIdx.x;
    const int row0 = blockIdx.x * 64;

    for (int i = tid; i < 2048; i += 256) {
        int r = i >> 4, off = (i & 15) * 8;
        *(uint4*)&Wsl[r][off] = *(const uint4*)(Wt + (size_t)r * DD + off);
    }
    for (int i = tid; i < 2048; i += 256) {
        int r = i >> 5, off4 = i & 31;
        int grow = row0 + r;
        float4 v = make_float4(0.f, 0.f, 0.f, 0.f);
        if (grow < nrows)
            v = *(const float4*)(A + (size_t)grow * DD + off4 * 4);
        if (doBN) {
            float4 sc = *(const float4*)(scale + off4 * 4);
            float4 sh = *(const float4*)(shift + off4 * 4);
            v.x = fmaxf(0.f, v.x * sc.x + sh.x);
            v.y = fmaxf(0.f, v.y * sc.y + sh.y);
            v.z = fmaxf(0.f, v.z * sc.z + sh.z);
            v.w = fmaxf(0.f, v.w * sc.w + sh.w);
        }
        ushort4 p;
        p.x = f2bf(v.x); p.y = f2bf(v.y); p.z = f2bf(v.z); p.w = f2bf(v.w);
        *(ushort4*)&Asl[r][off4 * 4] = p;
    }
    __syncthreads();

    const int w = tid >> 6, lane = tid & 63;
    const int m = lane & 15, q = lane >> 4;

    short8 afr[4];
    #pragma unroll
    for (int c = 0; c < 4; ++c)
        afr[c] = *(const short8*)&Asl[w * 16 + m][c * 32 + q * 8];

    float4v acc[8];
    #pragma unroll
    for (int t = 0; t < 8; ++t) acc[t] = (float4v){0.f, 0.f, 0.f, 0.f};

    #pragma unroll
    for (int t = 0; t < 8; ++t) {
        #pragma unroll
        for (int c = 0; c < 4; ++c) {
            short8 bfr = *(const short8*)&Wsl[t * 16 + m][c * 32 + q * 8];
            acc[t] = __builtin_amdgcn_mfma_f32_16x16x32_bf16(afr[c], bfr, acc[t], 0, 0, 0);
        }
    }

    #pragma unroll
    for (int t = 0; t < 8; ++t) {
        float bv = bias[t * 16 + m];
        #pragma unroll
        for (int i = 0; i < 4; ++i)
            Asl[w * 16 + q * 4 + i][t * 16 + m] = f2bf(acc[t][i] + bv);
    }
    __syncthreads();

    for (int i = tid; i < 1024; i += 256) {
        int r = i >> 4, off = (i & 15) * 8;
        if (row0 + r < nrows)
            *(uint4*)(H + (size_t)(row0 + r) * DD + off) = *(const uint4*)&Asl[r][off];
    }
}

// ---------------- SpMM: S_fp32 = A_csr @ H_bf16 ----------------
// 4 rows/block, 64 lanes/row, 2 channels/lane (bf16x2 = 4B coalesced loads)

__global__ __launch_bounds__(256) void spmm_bf16_kernel(
    const unsigned short* __restrict__ H, const int* __restrict__ row_start,
    const unsigned long long* __restrict__ ebuf,
    float* __restrict__ S, int N)
{
    int g = threadIdx.x >> 6, lane = threadIdx.x & 63;
    int r = blockIdx.x * 4 + g;
    if (r >= N) return;
    int e0 = row_start[r];
    int e1 = row_start[r + 1];
    float ax = 0.f, ay = 0.f;
    const unsigned short* Hp = H + lane * 2;
    int e = e0;
    for (; e + 1 < e1; e += 2) {
        unsigned long long p0 = ebuf[e], p1 = ebuf[e + 1];
        unsigned int c0 = (unsigned int)p0, c1 = (unsigned int)p1;
        float w0 = __uint_as_float((unsigned int)(p0 >> 32));
        float w1 = __uint_as_float((unsigned int)(p1 >> 32));
        unsigned int u0 = *(const unsigned int*)(Hp + (size_t)c0 * DD);
        unsigned int u1 = *(const unsigned int*)(Hp + (size_t)c1 * DD);
        ax += w0 * bfhi2f(u0 << 16);
        ay += w0 * bfhi2f(u0 & 0xffff0000u);
        ax += w1 * bfhi2f(u1 << 16);
        ay += w1 * bfhi2f(u1 & 0xffff0000u);
    }
    if (e < e1) {
        unsigned long long p0 = ebuf[e];
        unsigned int c0 = (unsigned int)p0;
        float w0 = __uint_as_float((unsigned int)(p0 >> 32));
        unsigned int u0 = *(const unsigned int*)(Hp + (size_t)c0 * DD);
        ax += w0 * bfhi2f(u0 << 16);
        ay += w0 * bfhi2f(u0 & 0xffff0000u);
    }
    float2 o; o.x = ax; o.y = ay;
    *(float2*)(S + (size_t)r * DD + lane * 2) = o;
}

// ---------------- BatchNorm stats + finalize ----------------

__global__ void bn_stats_kernel(const float* __restrict__ S, float* __restrict__ sums, int n) {
    __shared__ float ls[256], ls2[256];
    int tid = threadIdx.x;
    int c = tid & 127;
    float s = 0.f, s2 = 0.f;
    size_t total = (size_t)n * DD;
    #pragma unroll 8
    for (size_t i = (size_t)blockIdx.x * 256 + tid; i < total; i += (size_t)256 * 256) {
        float v = S[i];
        s += v;
        s2 += v * v;
    }
    ls[tid] = s;
    ls2[tid] = s2;
    __syncthreads();
    if (tid < 128) {
        s  = ls[tid] + ls[tid + 128];
        s2 = ls2[tid] + ls2[tid + 128];
        atomicAdd(&sums[c], s);
        atomicAdd(&sums[128 + c], s2);
    }
}

__global__ void bn_final_kernel(const float* __restrict__ sums, const float* __restrict__ g,
                                const float* __restrict__ be, float* __restrict__ scl,
                                float* __restrict__ sft, int n) {
    int c = threadIdx.x;
    float mean = sums[c] / (float)n;
    float var = sums[128 + c] / (float)n - mean * mean;
    float rstd = rsqrtf(var + EPS);
    float sc = g[c] * rstd;
    scl[c] = sc;
    sft[c] = be[c] - mean * sc;
}

// ---------------- launch ----------------

extern "C" void kernel_launch(void* const* d_in, const int* in_sizes, int n_in,
                              void* d_out, int out_size, void* d_ws, size_t ws_size,
                              hipStream_t stream) {
    const float* x   = (const float*)d_in[0];
    const float* ew  = (const float*)d_in[1];
    const float* W0  = (const float*)d_in[2];
    const float* b0  = (const float*)d_in[3];
    const float* g0  = (const float*)d_in[4];
    const float* be0 = (const float*)d_in[5];
    const float* W1  = (const float*)d_in[6];
    const float* b1  = (const float*)d_in[7];
    const float* g1  = (const float*)d_in[8];
    const float* be1 = (const float*)d_in[9];
    const float* W2  = (const float*)d_in[10];
    const float* b2  = (const float*)d_in[11];
    const int* row   = (const int*)d_in[12];
    const int* col   = (const int*)d_in[13];

    const int N = in_sizes[0] / DD;
    const int E = in_sizes[1];
    float* out = (float*)d_out;

    char* w = (char*)d_ws;
    unsigned short* H   = (unsigned short*)w; w += (size_t)N * DD * 2;
    unsigned long long* ebuf = (unsigned long long*)w; w += (size_t)E * 8;
    unsigned short* Wt0 = (unsigned short*)w; w += DD * DD * 2;
    unsigned short* Wt1 = (unsigned short*)w; w += DD * DD * 2;
    unsigned short* Wt2 = (unsigned short*)w; w += DD * DD * 2;
    float* sums         = (float*)w;          w += 256 * 4;
    float* scl          = (float*)w;          w += 128 * 4;
    float* sft          = (float*)w;          w += 128 * 4;
    int*   deg          = (int*)w;            w += (size_t)N * 4;
    int*   tmp          = (int*)w;            w += (size_t)N * 4;
    int*   cursor       = (int*)w;            w += (size_t)N * 4;
    int*   bsum         = (int*)w;            w += 128 * 4;
    int*   boff         = (int*)w;            w += 128 * 4;
    int*   row_start    = (int*)w;            w += (size_t)(N + 1) * 4;

    // ---- CSR build (reused by all 3 SpMMs) ----
    hipMemsetAsync(deg, 0, (size_t)N * 4, stream);
    hist_kernel<<<(E + 255) / 256, 256, 0, stream>>>(row, deg, E);
    int NB = (N + 1023) / 1024;
    scanA_kernel<<<NB, 1024, 0, stream>>>(deg, tmp, bsum, N);
    scanB_kernel<<<1, 128, 0, stream>>>(bsum, boff, row_start, NB, N);
    scanC_kernel<<<NB, 1024, 0, stream>>>(deg, tmp, boff, row_start, cursor, N);
    scatter_kernel<<<(E + 255) / 256, 256, 0, stream>>>(row, col, ew, cursor, ebuf, E);

    // ---- weights -> bf16 transposed ----
    convw_kernel<<<dim3(64, 3), 256, 0, stream>>>(W0, W1, W2, Wt0, Wt1, Wt2);

    int gblocks = (N + 63) / 64;
    int sblocks = (N + 3) / 4;

    // ---- layer 0 ----
    gemm_mfma_kernel<<<gblocks, 256, 0, stream>>>(x, Wt0, b0, nullptr, nullptr, 0, H, N);
    spmm_bf16_kernel<<<sblocks, 256, 0, stream>>>(H, row_start, ebuf, out, N);
    hipMemsetAsync(sums, 0, 256 * 4, stream);
    bn_stats_kernel<<<256, 256, 0, stream>>>(out, sums, N);
    bn_final_kernel<<<1, 128, 0, stream>>>(sums, g0, be0, scl, sft, N);

    // ---- layer 1 ----
    gemm_mfma_kernel<<<gblocks, 256, 0, stream>>>(out, Wt1, b1, scl, sft, 1, H, N);
    spmm_bf16_kernel<<<sblocks, 256, 0, stream>>>(H, row_start, ebuf, out, N);
    hipMemsetAsync(sums, 0, 256 * 4, stream);
    bn_stats_kernel<<<256, 256, 0, stream>>>(out, sums, N);
    bn_final_kernel<<<1, 128, 0, stream>>>(sums, g1, be1, scl, sft, N);

    // ---- layer 2 (no BN/ReLU) ----
    gemm_mfma_kernel<<<gblocks, 256, 0, stream>>>(out, Wt2, b2, scl, sft, 1, H, N);
    spmm_bf16_kernel<<<sblocks, 256, 0, stream>>>(H, row_start, ebuf, out, N);
}

// Round 5
// 675.754 us; speedup vs baseline: 6.7900x; 1.0870x over previous
//
#include <hip/hip_runtime.h>
#include <cstddef>

#define DD 128
#define EPS 1e-5f

typedef short short8 __attribute__((ext_vector_type(8)));
typedef float float4v __attribute__((ext_vector_type(4)));

__device__ __forceinline__ unsigned short f2bf(float f) {
    union { float f; unsigned int u; } x; x.f = f;
    unsigned int r = x.u + 0x7fffu + ((x.u >> 16) & 1u);   // RNE
    return (unsigned short)(r >> 16);
}
__device__ __forceinline__ float bfhi2f(unsigned int hi_bits) {
    union { unsigned int u; float f; } x; x.u = hi_bits;
    return x.f;
}

// ---------------- CSR build ----------------

__global__ void hist_kernel(const int* __restrict__ row, int* __restrict__ deg, int E) {
    int e = blockIdx.x * blockDim.x + threadIdx.x;
    if (e < E) atomicAdd(&deg[row[e]], 1);
}

__global__ void scanA_kernel(const int* __restrict__ deg, int* __restrict__ tmp,
                             int* __restrict__ bsum, int n) {
    __shared__ int s[1024];
    int tid = threadIdx.x;
    int gid = blockIdx.x * 1024 + tid;
    int v = (gid < n) ? deg[gid] : 0;
    s[tid] = v;
    __syncthreads();
    for (int off = 1; off < 1024; off <<= 1) {
        int t = s[tid];
        int u = (tid >= off) ? s[tid - off] : 0;
        __syncthreads();
        s[tid] = t + u;
        __syncthreads();
    }
    if (gid < n) tmp[gid] = s[tid];
    if (tid == 1023) bsum[blockIdx.x] = s[1023];
}

__global__ void scanB_kernel(const int* __restrict__ bsum, int* __restrict__ boff,
                             int* __restrict__ row_start, int nb, int n) {
    __shared__ int s[128];
    int tid = threadIdx.x;
    int v = (tid < nb) ? bsum[tid] : 0;
    s[tid] = v;
    __syncthreads();
    for (int off = 1; off < 128; off <<= 1) {
        int t = s[tid];
        int u = (tid >= off) ? s[tid - off] : 0;
        __syncthreads();
        s[tid] = t + u;
        __syncthreads();
    }
    if (tid < nb) boff[tid] = s[tid] - v;
    if (tid == nb - 1) row_start[n] = s[tid];
}

__global__ void scanC_kernel(const int* __restrict__ deg, const int* __restrict__ tmp,
                             const int* __restrict__ boff, int* __restrict__ row_start,
                             int* __restrict__ cursor, int n) {
    int gid = blockIdx.x * 1024 + threadIdx.x;
    if (gid < n) {
        int rs = tmp[gid] - deg[gid] + boff[blockIdx.x];
        row_start[gid] = rs;
        cursor[gid] = rs;
    }
}

// ---------------- XCD-bucketed scatter ----------------
// 8 row-buckets (balanced via magic-mul r*8/N). blockIdx&7 = bucket; with
// round-robin block->XCD dispatch, each bucket's ~1.6MB CSR window is written
// by ONE XCD only -> lines accumulate ~8 records in that L2 before writeback.
// Reads are 8x-amplified but shared across sibling blocks (L3 absorbs).
#define SCHUNK 2048

__global__ __launch_bounds__(256) void scatter_bucketed_kernel(
    const int* __restrict__ row, const int* __restrict__ col,
    const float* __restrict__ ew, int* __restrict__ cursor,
    unsigned long long* __restrict__ ebuf, int E, unsigned int bmagic) {
    int chunk = blockIdx.x >> 3;
    unsigned int bucket = blockIdx.x & 7;
    int base = chunk * SCHUNK + threadIdx.x;
    #pragma unroll
    for (int i = 0; i < SCHUNK / 256; ++i) {
        int e = base + i * 256;
        if (e < E) {
            int r = row[e];
            if (__umulhi((unsigned int)r, bmagic) == bucket) {
                int p = atomicAdd(&cursor[r], 1);
                unsigned long long pk = (unsigned long long)(unsigned int)col[e]
                                      | ((unsigned long long)__float_as_uint(ew[e]) << 32);
                ebuf[p] = pk;   // plain store: let the (XCD-local) L2 merge lines
            }
        }
    }
}

// ---------------- W -> W^T bf16 ----------------

__global__ void convw_kernel(const float* __restrict__ W0, const float* __restrict__ W1,
                             const float* __restrict__ W2, unsigned short* __restrict__ T0,
                             unsigned short* __restrict__ T1, unsigned short* __restrict__ T2) {
    const float* W = (blockIdx.y == 0) ? W0 : (blockIdx.y == 1) ? W1 : W2;
    unsigned short* T = (blockIdx.y == 0) ? T0 : (blockIdx.y == 1) ? T1 : T2;
    int gid = blockIdx.x * 256 + threadIdx.x;
    int k = gid >> 7, n = gid & 127;
    T[n * DD + k] = f2bf(W[k * DD + n]);
}

// ---------------- MFMA GEMM: H_bf16 = f(A_fp32) @ W + b ----------------
// BN finalize fused: scale/shift computed per-block from channel sums.

__global__ __launch_bounds__(256) void gemm_mfma_kernel(
    const float* __restrict__ A, const unsigned short* __restrict__ Wt,
    const float* __restrict__ bias,
    const float* __restrict__ sums, const float* __restrict__ g,
    const float* __restrict__ be,
    int doBN, unsigned short* __restrict__ H, int nrows)
{
    __shared__ unsigned short Asl[64][136];
    __shared__ unsigned short Wsl[128][136];
    __shared__ float scl_s[128], sft_s[128];

    const int tid  = threadIdx.x;
    const int row0 = blockIdx.x * 64;

    if (doBN && tid < 128) {
        float inv_n = 1.0f / (float)nrows;
        float mean = sums[tid] * inv_n;
        float var = sums[128 + tid] * inv_n - mean * mean;
        float rstd = rsqrtf(var + EPS);
        float sc = g[tid] * rstd;
        scl_s[tid] = sc;
        sft_s[tid] = be[tid] - mean * sc;
    }
    if (doBN) __syncthreads();

    for (int i = tid; i < 2048; i += 256) {
        int r = i >> 4, off = (i & 15) * 8;
        *(uint4*)&Wsl[r][off] = *(const uint4*)(Wt + (size_t)r * DD + off);
    }
    for (int i = tid; i < 2048; i += 256) {
        int r = i >> 5, off4 = i & 31;
        int grow = row0 + r;
        float4 v = make_float4(0.f, 0.f, 0.f, 0.f);
        if (grow < nrows)
            v = *(const float4*)(A + (size_t)grow * DD + off4 * 4);
        if (doBN) {
            float4 sc = *(const float4*)&scl_s[off4 * 4];
            float4 sh = *(const float4*)&sft_s[off4 * 4];
            v.x = fmaxf(0.f, v.x * sc.x + sh.x);
            v.y = fmaxf(0.f, v.y * sc.y + sh.y);
            v.z = fmaxf(0.f, v.z * sc.z + sh.z);
            v.w = fmaxf(0.f, v.w * sc.w + sh.w);
        }
        ushort4 p;
        p.x = f2bf(v.x); p.y = f2bf(v.y); p.z = f2bf(v.z); p.w = f2bf(v.w);
        *(ushort4*)&Asl[r][off4 * 4] = p;
    }
    __syncthreads();

    const int w = tid >> 6, lane = tid & 63;
    const int m = lane & 15, q = lane >> 4;

    short8 afr[4];
    #pragma unroll
    for (int c = 0; c < 4; ++c)
        afr[c] = *(const short8*)&Asl[w * 16 + m][c * 32 + q * 8];

    float4v acc[8];
    #pragma unroll
    for (int t = 0; t < 8; ++t) acc[t] = (float4v){0.f, 0.f, 0.f, 0.f};

    #pragma unroll
    for (int t = 0; t < 8; ++t) {
        #pragma unroll
        for (int c = 0; c < 4; ++c) {
            short8 bfr = *(const short8*)&Wsl[t * 16 + m][c * 32 + q * 8];
            acc[t] = __builtin_amdgcn_mfma_f32_16x16x32_bf16(afr[c], bfr, acc[t], 0, 0, 0);
        }
    }

    #pragma unroll
    for (int t = 0; t < 8; ++t) {
        float bv = bias[t * 16 + m];
        #pragma unroll
        for (int i = 0; i < 4; ++i)
            Asl[w * 16 + q * 4 + i][t * 16 + m] = f2bf(acc[t][i] + bv);
    }
    __syncthreads();

    for (int i = tid; i < 1024; i += 256) {
        int r = i >> 4, off = (i & 15) * 8;
        if (row0 + r < nrows)
            *(uint4*)(H + (size_t)(row0 + r) * DD + off) = *(const uint4*)&Asl[r][off];
    }
}

// ---------------- SpMM: S_fp32 = A_csr @ H_bf16 ----------------
// 4 rows/block, 64 lanes/row, 2 channels/lane; 4-edge software pipeline
// (4 H-gathers in flight before accumulation).

__global__ __launch_bounds__(256) void spmm_bf16_kernel(
    const unsigned short* __restrict__ H, const int* __restrict__ row_start,
    const unsigned long long* __restrict__ ebuf,
    float* __restrict__ S, int N)
{
    int g = threadIdx.x >> 6, lane = threadIdx.x & 63;
    int r = blockIdx.x * 4 + g;
    if (r >= N) return;
    int e0 = row_start[r];
    int e1 = row_start[r + 1];
    float ax = 0.f, ay = 0.f;
    const unsigned short* Hp = H + lane * 2;
    int e = e0;
    for (; e + 3 < e1; e += 4) {
        unsigned long long p0 = __builtin_nontemporal_load(&ebuf[e]);
        unsigned long long p1 = __builtin_nontemporal_load(&ebuf[e + 1]);
        unsigned long long p2 = __builtin_nontemporal_load(&ebuf[e + 2]);
        unsigned long long p3 = __builtin_nontemporal_load(&ebuf[e + 3]);
        unsigned int u0 = *(const unsigned int*)(Hp + (size_t)(unsigned int)p0 * DD);
        unsigned int u1 = *(const unsigned int*)(Hp + (size_t)(unsigned int)p1 * DD);
        unsigned int u2 = *(const unsigned int*)(Hp + (size_t)(unsigned int)p2 * DD);
        unsigned int u3 = *(const unsigned int*)(Hp + (size_t)(unsigned int)p3 * DD);
        float w0 = __uint_as_float((unsigned int)(p0 >> 32));
        float w1 = __uint_as_float((unsigned int)(p1 >> 32));
        float w2 = __uint_as_float((unsigned int)(p2 >> 32));
        float w3 = __uint_as_float((unsigned int)(p3 >> 32));
        ax += w0 * bfhi2f(u0 << 16);
        ay += w0 * bfhi2f(u0 & 0xffff0000u);
        ax += w1 * bfhi2f(u1 << 16);
        ay += w1 * bfhi2f(u1 & 0xffff0000u);
        ax += w2 * bfhi2f(u2 << 16);
        ay += w2 * bfhi2f(u2 & 0xffff0000u);
        ax += w3 * bfhi2f(u3 << 16);
        ay += w3 * bfhi2f(u3 & 0xffff0000u);
    }
    for (; e < e1; ++e) {
        unsigned long long p0 = __builtin_nontemporal_load(&ebuf[e]);
        unsigned int u0 = *(const unsigned int*)(Hp + (size_t)(unsigned int)p0 * DD);
        float w0 = __uint_as_float((unsigned int)(p0 >> 32));
        ax += w0 * bfhi2f(u0 << 16);
        ay += w0 * bfhi2f(u0 & 0xffff0000u);
    }
    float2 o; o.x = ax; o.y = ay;
    *(float2*)(S + (size_t)r * DD + lane * 2) = o;
}

// ---------------- BatchNorm stats ----------------

__global__ void bn_stats_kernel(const float* __restrict__ S, float* __restrict__ sums, int n) {
    __shared__ float ls[256], ls2[256];
    int tid = threadIdx.x;
    int c = tid & 127;
    float s = 0.f, s2 = 0.f;
    size_t total = (size_t)n * DD;
    #pragma unroll 8
    for (size_t i = (size_t)blockIdx.x * 256 + tid; i < total; i += (size_t)256 * 256) {
        float v = S[i];
        s += v;
        s2 += v * v;
    }
    ls[tid] = s;
    ls2[tid] = s2;
    __syncthreads();
    if (tid < 128) {
        s  = ls[tid] + ls[tid + 128];
        s2 = ls2[tid] + ls2[tid + 128];
        atomicAdd(&sums[c], s);
        atomicAdd(&sums[128 + c], s2);
    }
}

// ---------------- launch ----------------

extern "C" void kernel_launch(void* const* d_in, const int* in_sizes, int n_in,
                              void* d_out, int out_size, void* d_ws, size_t ws_size,
                              hipStream_t stream) {
    const float* x   = (const float*)d_in[0];
    const float* ew  = (const float*)d_in[1];
    const float* W0  = (const float*)d_in[2];
    const float* b0  = (const float*)d_in[3];
    const float* g0  = (const float*)d_in[4];
    const float* be0 = (const float*)d_in[5];
    const float* W1  = (const float*)d_in[6];
    const float* b1  = (const float*)d_in[7];
    const float* g1  = (const float*)d_in[8];
    const float* be1 = (const float*)d_in[9];
    const float* W2  = (const float*)d_in[10];
    const float* b2  = (const float*)d_in[11];
    const int* row   = (const int*)d_in[12];
    const int* col   = (const int*)d_in[13];

    const int N = in_sizes[0] / DD;
    const int E = in_sizes[1];
    float* out = (float*)d_out;

    char* w = (char*)d_ws;
    unsigned short* H   = (unsigned short*)w; w += (size_t)N * DD * 2;
    unsigned long long* ebuf = (unsigned long long*)w; w += (size_t)E * 8;
    unsigned short* Wt0 = (unsigned short*)w; w += DD * DD * 2;
    unsigned short* Wt1 = (unsigned short*)w; w += DD * DD * 2;
    unsigned short* Wt2 = (unsigned short*)w; w += DD * DD * 2;
    float* sums         = (float*)w;          w += 256 * 4;
    int*   deg          = (int*)w;            w += (size_t)N * 4;
    int*   tmp          = (int*)w;            w += (size_t)N * 4;
    int*   cursor       = (int*)w;            w += (size_t)N * 4;
    int*   bsum         = (int*)w;            w += 128 * 4;
    int*   boff         = (int*)w;            w += 128 * 4;
    int*   row_start    = (int*)w;            w += (size_t)(N + 1) * 4;

    // bucket magic: bucket(r) = (r * 8) / N  via  umulhi(r, floor(8*2^32/N))
    unsigned int bmagic = (unsigned int)(((unsigned long long)8 << 32) / (unsigned long long)N);

    // ---- CSR build (reused by all 3 SpMMs) ----
    hipMemsetAsync(deg, 0, (size_t)N * 4, stream);
    hist_kernel<<<(E + 255) / 256, 256, 0, stream>>>(row, deg, E);
    int NB = (N + 1023) / 1024;
    scanA_kernel<<<NB, 1024, 0, stream>>>(deg, tmp, bsum, N);
    scanB_kernel<<<1, 128, 0, stream>>>(bsum, boff, row_start, NB, N);
    scanC_kernel<<<NB, 1024, 0, stream>>>(deg, tmp, boff, row_start, cursor, N);
    int nchunks = (E + SCHUNK - 1) / SCHUNK;
    scatter_bucketed_kernel<<<nchunks * 8, 256, 0, stream>>>(row, col, ew, cursor, ebuf, E, bmagic);

    // ---- weights -> bf16 transposed ----
    convw_kernel<<<dim3(64, 3), 256, 0, stream>>>(W0, W1, W2, Wt0, Wt1, Wt2);

    int gblocks = (N + 63) / 64;
    int sblocks = (N + 3) / 4;

    // ---- layer 0 ----
    gemm_mfma_kernel<<<gblocks, 256, 0, stream>>>(x, Wt0, b0, nullptr, nullptr, nullptr, 0, H, N);
    spmm_bf16_kernel<<<sblocks, 256, 0, stream>>>(H, row_start, ebuf, out, N);
    hipMemsetAsync(sums, 0, 256 * 4, stream);
    bn_stats_kernel<<<256, 256, 0, stream>>>(out, sums, N);

    // ---- layer 1 ----
    gemm_mfma_kernel<<<gblocks, 256, 0, stream>>>(out, Wt1, b1, sums, g0, be0, 1, H, N);
    spmm_bf16_kernel<<<sblocks, 256, 0, stream>>>(H, row_start, ebuf, out, N);
    hipMemsetAsync(sums, 0, 256 * 4, stream);
    bn_stats_kernel<<<256, 256, 0, stream>>>(out, sums, N);

    // ---- layer 2 (no BN/ReLU after) ----
    gemm_mfma_kernel<<<gblocks, 256, 0, stream>>>(out, Wt2, b2, sums, g1, be1, 1, H, N);
    spmm_bf16_kernel<<<sblocks, 256, 0, stream>>>(H, row_start, ebuf, out, N);
}

// Round 7
// 630.113 us; speedup vs baseline: 7.2819x; 1.0724x over previous
//
#include <hip/hip_runtime.h>
#include <cstddef>

#define DD 128
#define EPS 1e-5f

typedef short short8 __attribute__((ext_vector_type(8)));
typedef float float4v __attribute__((ext_vector_type(4)));

__device__ __forceinline__ unsigned short f2bf(float f) {
    union { float f; unsigned int u; } x; x.f = f;
    unsigned int r = x.u + 0x7fffu + ((x.u >> 16) & 1u);   // RNE
    return (unsigned short)(r >> 16);
}
__device__ __forceinline__ float bfhi2f(unsigned int hi_bits) {
    union { unsigned int u; float f; } x; x.u = hi_bits;
    return x.f;
}

// ---------------- CSR build ----------------

__global__ void hist_kernel(const int* __restrict__ row, int* __restrict__ deg, int E) {
    int e = blockIdx.x * blockDim.x + threadIdx.x;
    if (e < E) atomicAdd(&deg[row[e]], 1);
}

__global__ void scanA_kernel(const int* __restrict__ deg, int* __restrict__ tmp,
                             int* __restrict__ bsum, int n) {
    __shared__ int s[1024];
    int tid = threadIdx.x;
    int gid = blockIdx.x * 1024 + tid;
    int v = (gid < n) ? deg[gid] : 0;
    s[tid] = v;
    __syncthreads();
    for (int off = 1; off < 1024; off <<= 1) {
        int t = s[tid];
        int u = (tid >= off) ? s[tid - off] : 0;
        __syncthreads();
        s[tid] = t + u;
        __syncthreads();
    }
    if (gid < n) tmp[gid] = s[tid];
    if (tid == 1023) bsum[blockIdx.x] = s[1023];
}

__global__ void scanB_kernel(const int* __restrict__ bsum, int* __restrict__ boff,
                             int* __restrict__ row_start, int nb, int n) {
    __shared__ int s[128];
    int tid = threadIdx.x;
    int v = (tid < nb) ? bsum[tid] : 0;
    s[tid] = v;
    __syncthreads();
    for (int off = 1; off < 128; off <<= 1) {
        int t = s[tid];
        int u = (tid >= off) ? s[tid - off] : 0;
        __syncthreads();
        s[tid] = t + u;
        __syncthreads();
    }
    if (tid < nb) boff[tid] = s[tid] - v;
    if (tid == nb - 1) row_start[n] = s[tid];
}

__global__ void scanC_kernel(const int* __restrict__ deg, const int* __restrict__ tmp,
                             const int* __restrict__ boff, int* __restrict__ row_start,
                             int* __restrict__ cursor, int n) {
    int gid = blockIdx.x * 1024 + threadIdx.x;
    if (gid < n) {
        int rs = tmp[gid] - deg[gid] + boff[blockIdx.x];
        row_start[gid] = rs;
        cursor[gid] = rs;
    }
}

// ---------------- XCD-bucketed scatter ----------------
#define SCHUNK 2048

__global__ __launch_bounds__(256) void scatter_bucketed_kernel(
    const int* __restrict__ row, const int* __restrict__ col,
    const float* __restrict__ ew, int* __restrict__ cursor,
    unsigned long long* __restrict__ ebuf, int E, unsigned int bmagic) {
    int chunk = blockIdx.x >> 3;
    unsigned int bucket = blockIdx.x & 7;
    int base = chunk * SCHUNK + threadIdx.x;
    #pragma unroll
    for (int i = 0; i < SCHUNK / 256; ++i) {
        int e = base + i * 256;
        if (e < E) {
            int r = row[e];
            if (__umulhi((unsigned int)r, bmagic) == bucket) {
                int p = atomicAdd(&cursor[r], 1);
                unsigned long long pk = (unsigned long long)(unsigned int)col[e]
                                      | ((unsigned long long)__float_as_uint(ew[e]) << 32);
                ebuf[p] = pk;   // plain store: XCD-local L2 merges lines
            }
        }
    }
}

// ---------------- W -> W^T bf16 ----------------

__global__ void convw_kernel(const float* __restrict__ W0, const float* __restrict__ W1,
                             const float* __restrict__ W2, unsigned short* __restrict__ T0,
                             unsigned short* __restrict__ T1, unsigned short* __restrict__ T2) {
    const float* W = (blockIdx.y == 0) ? W0 : (blockIdx.y == 1) ? W1 : W2;
    unsigned short* T = (blockIdx.y == 0) ? T0 : (blockIdx.y == 1) ? T1 : T2;
    int gid = blockIdx.x * 256 + threadIdx.x;
    int k = gid >> 7, n = gid & 127;
    T[n * DD + k] = f2bf(W[k * DD + n]);
}

// ---------------- MFMA GEMM (layer 0): H_bf16 = A_fp32 @ W + b ----------------

__global__ __launch_bounds__(256) void gemm_mfma_f32_kernel(
    const float* __restrict__ A, const unsigned short* __restrict__ Wt,
    const float* __restrict__ bias, unsigned short* __restrict__ H, int nrows)
{
    __shared__ unsigned short Asl[64][136];
    __shared__ unsigned short Wsl[128][136];

    const int tid  = threadIdx.x;
    const int row0 = blockIdx.x * 64;

    for (int i = tid; i < 2048; i += 256) {
        int r = i >> 4, off = (i & 15) * 8;
        *(uint4*)&Wsl[r][off] = *(const uint4*)(Wt + (size_t)r * DD + off);
    }
    for (int i = tid; i < 2048; i += 256) {
        int r = i >> 5, off4 = i & 31;
        int grow = row0 + r;
        float4 v = make_float4(0.f, 0.f, 0.f, 0.f);
        if (grow < nrows)
            v = *(const float4*)(A + (size_t)grow * DD + off4 * 4);
        ushort4 p;
        p.x = f2bf(v.x); p.y = f2bf(v.y); p.z = f2bf(v.z); p.w = f2bf(v.w);
        *(ushort4*)&Asl[r][off4 * 4] = p;
    }
    __syncthreads();

    const int w = tid >> 6, lane = tid & 63;
    const int m = lane & 15, q = lane >> 4;

    short8 afr[4];
    #pragma unroll
    for (int c = 0; c < 4; ++c)
        afr[c] = *(const short8*)&Asl[w * 16 + m][c * 32 + q * 8];

    float4v acc[8];
    #pragma unroll
    for (int t = 0; t < 8; ++t) acc[t] = (float4v){0.f, 0.f, 0.f, 0.f};

    #pragma unroll
    for (int t = 0; t < 8; ++t) {
        #pragma unroll
        for (int c = 0; c < 4; ++c) {
            short8 bfr = *(const short8*)&Wsl[t * 16 + m][c * 32 + q * 8];
            acc[t] = __builtin_amdgcn_mfma_f32_16x16x32_bf16(afr[c], bfr, acc[t], 0, 0, 0);
        }
    }

    #pragma unroll
    for (int t = 0; t < 8; ++t) {
        float bv = bias[t * 16 + m];
        #pragma unroll
        for (int i = 0; i < 4; ++i)
            Asl[w * 16 + q * 4 + i][t * 16 + m] = f2bf(acc[t][i] + bv);
    }
    __syncthreads();

    for (int i = tid; i < 1024; i += 256) {
        int r = i >> 4, off = (i & 15) * 8;
        if (row0 + r < nrows)
            *(uint4*)(H + (size_t)(row0 + r) * DD + off) = *(const uint4*)&Asl[r][off];
    }
}

// ---------------- MFMA GEMM (layers 1/2): H_bf16 = relu(bn(A_bf16)) @ W + b ----------------
// BN finalize fused (scale/shift from channel sums); A is bf16 pairs (uint = 2 ch).

__global__ __launch_bounds__(256) void gemm_mfma_bf16_kernel(
    const unsigned int* __restrict__ A, const unsigned short* __restrict__ Wt,
    const float* __restrict__ bias,
    const float* __restrict__ sums, const float* __restrict__ g,
    const float* __restrict__ be,
    unsigned short* __restrict__ H, int nrows)
{
    __shared__ unsigned short Asl[64][136];
    __shared__ unsigned short Wsl[128][136];
    __shared__ float scl_s[128], sft_s[128];

    const int tid  = threadIdx.x;
    const int row0 = blockIdx.x * 64;

    if (tid < 128) {
        float inv_n = 1.0f / (float)nrows;
        float mean = sums[tid] * inv_n;
        float var = sums[128 + tid] * inv_n - mean * mean;
        float rstd = rsqrtf(var + EPS);
        float sc = g[tid] * rstd;
        scl_s[tid] = sc;
        sft_s[tid] = be[tid] - mean * sc;
    }

    for (int i = tid; i < 2048; i += 256) {
        int r = i >> 4, off = (i & 15) * 8;
        *(uint4*)&Wsl[r][off] = *(const uint4*)(Wt + (size_t)r * DD + off);
    }
    __syncthreads();

    // stage A: 64 rows x 16 chunks of 8 bf16 (uint4 = 4 packed ch-pairs)
    for (int i = tid; i < 1024; i += 256) {
        int r = i >> 4, ch = (i & 15) * 8;     // channel base
        int grow = row0 + r;
        uint4 u = make_uint4(0, 0, 0, 0);
        if (grow < nrows)
            u = *(const uint4*)(A + (size_t)grow * 64 + (ch >> 1));
        unsigned int uu[4] = {u.x, u.y, u.z, u.w};
        unsigned int outp[4];
        #pragma unroll
        for (int j = 0; j < 4; ++j) {
            float vx = bfhi2f(uu[j] << 16);
            float vy = bfhi2f(uu[j] & 0xffff0000u);
            int k = ch + j * 2;
            vx = fmaxf(0.f, vx * scl_s[k] + sft_s[k]);
            vy = fmaxf(0.f, vy * scl_s[k + 1] + sft_s[k + 1]);
            outp[j] = (unsigned int)f2bf(vx) | ((unsigned int)f2bf(vy) << 16);
        }
        *(uint4*)&Asl[r][ch] = *(const uint4*)outp;
    }
    __syncthreads();

    const int w = tid >> 6, lane = tid & 63;
    const int m = lane & 15, q = lane >> 4;

    short8 afr[4];
    #pragma unroll
    for (int c = 0; c < 4; ++c)
        afr[c] = *(const short8*)&Asl[w * 16 + m][c * 32 + q * 8];

    float4v acc[8];
    #pragma unroll
    for (int t = 0; t < 8; ++t) acc[t] = (float4v){0.f, 0.f, 0.f, 0.f};

    #pragma unroll
    for (int t = 0; t < 8; ++t) {
        #pragma unroll
        for (int c = 0; c < 4; ++c) {
            short8 bfr = *(const short8*)&Wsl[t * 16 + m][c * 32 + q * 8];
            acc[t] = __builtin_amdgcn_mfma_f32_16x16x32_bf16(afr[c], bfr, acc[t], 0, 0, 0);
        }
    }

    #pragma unroll
    for (int t = 0; t < 8; ++t) {
        float bv = bias[t * 16 + m];
        #pragma unroll
        for (int i = 0; i < 4; ++i)
            Asl[w * 16 + q * 4 + i][t * 16 + m] = f2bf(acc[t][i] + bv);
    }
    __syncthreads();

    for (int i = tid; i < 1024; i += 256) {
        int r = i >> 4, off = (i & 15) * 8;
        if (row0 + r < nrows)
            *(uint4*)(H + (size_t)(row0 + r) * DD + off) = *(const uint4*)&Asl[r][off];
    }
}

// ---------------- SpMM: S = A_csr @ H_bf16 ----------------
// 4 rows/block, 64 lanes/row, 2 ch/lane; 8-deep gather pipeline.
// writeBF=1: S as packed bf16 pairs (layers 0/1); else fp32 (final).

__global__ __launch_bounds__(256) void spmm_bf16_kernel(
    const unsigned short* __restrict__ H, const int* __restrict__ row_start,
    const unsigned long long* __restrict__ ebuf,
    float* __restrict__ Sf, unsigned int* __restrict__ Sb, int writeBF, int N)
{
    int g = threadIdx.x >> 6, lane = threadIdx.x & 63;
    int r = blockIdx.x * 4 + g;
    if (r >= N) return;
    int e0 = row_start[r], e1 = row_start[r + 1];
    const unsigned short* Hp = H + lane * 2;
    float ax = 0.f, ay = 0.f;
    int e = e0;
    for (; e + 7 < e1; e += 8) {
        unsigned long long p[8];
        #pragma unroll
        for (int j = 0; j < 8; ++j) p[j] = __builtin_nontemporal_load(&ebuf[e + j]);
        unsigned int u[8];
        #pragma unroll
        for (int j = 0; j < 8; ++j)
            u[j] = *(const unsigned int*)(Hp + (size_t)(unsigned int)p[j] * DD);
        #pragma unroll
        for (int j = 0; j < 8; ++j) {
            float wj = __uint_as_float((unsigned int)(p[j] >> 32));
            ax += wj * bfhi2f(u[j] << 16);
            ay += wj * bfhi2f(u[j] & 0xffff0000u);
        }
    }
    if (e + 3 < e1) {
        unsigned long long p[4];
        #pragma unroll
        for (int j = 0; j < 4; ++j) p[j] = __builtin_nontemporal_load(&ebuf[e + j]);
        unsigned int u[4];
        #pragma unroll
        for (int j = 0; j < 4; ++j)
            u[j] = *(const unsigned int*)(Hp + (size_t)(unsigned int)p[j] * DD);
        #pragma unroll
        for (int j = 0; j < 4; ++j) {
            float wj = __uint_as_float((unsigned int)(p[j] >> 32));
            ax += wj * bfhi2f(u[j] << 16);
            ay += wj * bfhi2f(u[j] & 0xffff0000u);
        }
        e += 4;
    }
    for (; e < e1; ++e) {
        unsigned long long p0 = __builtin_nontemporal_load(&ebuf[e]);
        unsigned int u0 = *(const unsigned int*)(Hp + (size_t)(unsigned int)p0 * DD);
        float w0 = __uint_as_float((unsigned int)(p0 >> 32));
        ax += w0 * bfhi2f(u0 << 16);
        ay += w0 * bfhi2f(u0 & 0xffff0000u);
    }
    if (writeBF) {
        unsigned int pk = (unsigned int)f2bf(ax) | ((unsigned int)f2bf(ay) << 16);
        Sb[(size_t)r * 64 + lane] = pk;
    } else {
        float2 o; o.x = ax; o.y = ay;
        *(float2*)(Sf + (size_t)r * DD + lane * 2) = o;
    }
}

// ---------------- BatchNorm stats over bf16 S ----------------

__global__ void bn_stats_bf16_kernel(const unsigned int* __restrict__ Sb,
                                     float* __restrict__ sums, int n) {
    __shared__ float lsx[256], lsx2[256], lsy[256], lsy2[256];
    int tid = threadIdx.x;
    int c2 = tid & 63;      // pair index -> channels 2c2, 2c2+1
    float sx = 0.f, sx2 = 0.f, sy = 0.f, sy2 = 0.f;
    int total = n * 64;
    for (int i = blockIdx.x * 256 + tid; i < total; i += 256 * 256) {
        unsigned int u = Sb[i];
        float vx = bfhi2f(u << 16);
        float vy = bfhi2f(u & 0xffff0000u);
        sx += vx; sx2 += vx * vx;
        sy += vy; sy2 += vy * vy;
    }
    lsx[tid] = sx; lsx2[tid] = sx2; lsy[tid] = sy; lsy2[tid] = sy2;
    __syncthreads();
    if (tid < 64) {
        sx  = lsx[tid]  + lsx[tid + 64]  + lsx[tid + 128]  + lsx[tid + 192];
        sx2 = lsx2[tid] + lsx2[tid + 64] + lsx2[tid + 128] + lsx2[tid + 192];
        sy  = lsy[tid]  + lsy[tid + 64]  + lsy[tid + 128]  + lsy[tid + 192];
        sy2 = lsy2[tid] + lsy2[tid + 64] + lsy2[tid + 128] + lsy2[tid + 192];
        atomicAdd(&sums[2 * c2], sx);
        atomicAdd(&sums[2 * c2 + 1], sy);
        atomicAdd(&sums[128 + 2 * c2], sx2);
        atomicAdd(&sums[129 + 2 * c2], sy2);
    }
}

// ---------------- launch ----------------

extern "C" void kernel_launch(void* const* d_in, const int* in_sizes, int n_in,
                              void* d_out, int out_size, void* d_ws, size_t ws_size,
                              hipStream_t stream) {
    const float* x   = (const float*)d_in[0];
    const float* ew  = (const float*)d_in[1];
    const float* W0  = (const float*)d_in[2];
    const float* b0  = (const float*)d_in[3];
    const float* g0  = (const float*)d_in[4];
    const float* be0 = (const float*)d_in[5];
    const float* W1  = (const float*)d_in[6];
    const float* b1  = (const float*)d_in[7];
    const float* g1  = (const float*)d_in[8];
    const float* be1 = (const float*)d_in[9];
    const float* W2  = (const float*)d_in[10];
    const float* b2  = (const float*)d_in[11];
    const int* row   = (const int*)d_in[12];
    const int* col   = (const int*)d_in[13];

    const int N = in_sizes[0] / DD;
    const int E = in_sizes[1];
    float* out = (float*)d_out;

    char* w = (char*)d_ws;
    unsigned short* H   = (unsigned short*)w; w += (size_t)N * DD * 2;
    unsigned int* Sb    = (unsigned int*)w;   w += (size_t)N * 64 * 4;
    unsigned long long* ebuf = (unsigned long long*)w; w += (size_t)E * 8;
    unsigned short* Wt0 = (unsigned short*)w; w += DD * DD * 2;
    unsigned short* Wt1 = (unsigned short*)w; w += DD * DD * 2;
    unsigned short* Wt2 = (unsigned short*)w; w += DD * DD * 2;
    float* sums         = (float*)w;          w += 256 * 4;
    int*   deg          = (int*)w;            w += (size_t)N * 4;
    int*   tmp          = (int*)w;            w += (size_t)N * 4;
    int*   cursor       = (int*)w;            w += (size_t)N * 4;
    int*   bsum         = (int*)w;            w += 128 * 4;
    int*   boff         = (int*)w;            w += 128 * 4;
    int*   row_start    = (int*)w;            w += (size_t)(N + 1) * 4;

    unsigned int bmagic = (unsigned int)(((unsigned long long)8 << 32) / (unsigned long long)N);

    // ---- CSR build (reused by all 3 SpMMs) ----
    hipMemsetAsync(deg, 0, (size_t)N * 4, stream);
    hist_kernel<<<(E + 255) / 256, 256, 0, stream>>>(row, deg, E);
    int NB = (N + 1023) / 1024;
    scanA_kernel<<<NB, 1024, 0, stream>>>(deg, tmp, bsum, N);
    scanB_kernel<<<1, 128, 0, stream>>>(bsum, boff, row_start, NB, N);
    scanC_kernel<<<NB, 1024, 0, stream>>>(deg, tmp, boff, row_start, cursor, N);
    int nchunks = (E + SCHUNK - 1) / SCHUNK;
    scatter_bucketed_kernel<<<nchunks * 8, 256, 0, stream>>>(row, col, ew, cursor, ebuf, E, bmagic);

    convw_kernel<<<dim3(64, 3), 256, 0, stream>>>(W0, W1, W2, Wt0, Wt1, Wt2);

    int gblocks = (N + 63) / 64;
    int sblocks = (N + 3) / 4;

    // ---- layer 0 ----
    gemm_mfma_f32_kernel<<<gblocks, 256, 0, stream>>>(x, Wt0, b0, H, N);
    spmm_bf16_kernel<<<sblocks, 256, 0, stream>>>(H, row_start, ebuf, nullptr, Sb, 1, N);
    hipMemsetAsync(sums, 0, 256 * 4, stream);
    bn_stats_bf16_kernel<<<256, 256, 0, stream>>>(Sb, sums, N);

    // ---- layer 1 ----
    gemm_mfma_bf16_kernel<<<gblocks, 256, 0, stream>>>(Sb, Wt1, b1, sums, g0, be0, H, N);
    spmm_bf16_kernel<<<sblocks, 256, 0, stream>>>(H, row_start, ebuf, nullptr, Sb, 1, N);
    hipMemsetAsync(sums, 0, 256 * 4, stream);
    bn_stats_bf16_kernel<<<256, 256, 0, stream>>>(Sb, sums, N);

    // ---- layer 2 (final: fp32 out, no BN after) ----
    gemm_mfma_bf16_kernel<<<gblocks, 256, 0, stream>>>(Sb, Wt2, b2, sums, g1, be1, H, N);
    spmm_bf16_kernel<<<sblocks, 256, 0, stream>>>(H, row_start, ebuf, out, nullptr, 0, N);
}